// Round 7
// baseline (335.946 us; speedup 1.0000x reference)
//
#include <hip/hip_runtime.h>
#include <hip/hip_bf16.h>

// B=8, T=2048, D=1024, E=1024
//   k0 : WT = bf16(W^T)                 -> d_out[32MiB..34MiB] (dead before k4)
//   k00: xbf = bf16(x) [B][T][D]        -> d_ws[0:32MiB]   (dead before k2 writes S)
//        xT  = bf16(x^T) [B][D][T]      -> d_ws[64MiB..96MiB] (only if ws >= 96MiB)
//   k1 : y = bf16(xbf@WT^T + b)         -> d_out[0:32MiB]  (2-phase dbuf, BK=32)
//   k2 : S[b,t,s] = bf16(y_t.y_s/32)    -> d_ws, lower-triangle tiles (BK=32)
//   k2b_part: per-(chunk,col) partial (m,z) -> S dead zone rows 64..575
//   k2c_comb: combine partials -> m_s, r_s=1/z_s stash (rows 0..63)
//   k3 : P = exp(S-m_s)*r_s in place    (causal-restricted)
//   k4 : out = P @ x  fp32  — fast path: 2-phase dbuf from P and xT (BK=32).
//
// Round-7: GEMMs were latency-bound with nothing >30% busy (k2: Mfma 26.6,
//   VALU 22.6, L2 30%, occ 28% = 2 blocks/CU). BK 64->32 halves dbuf LDS to
//   32KiB -> 4 blocks/CU = 32 waves (full), doubling cross-block TLP that
//   hides each block's stage latency (m114/m97: implicit block overlap is the
//   pipelining). Round-3 already showed in-block deepening (3 slots, 96KiB)
//   loses the 2nd block and regresses — TLP is the right axis.
//
// MFMA 16x16x32 bf16 frag layouts (HW-verified):
//   A: lane holds A[m=lane&15][k=q*8+j]; B: B[k=q*8+j][n=lane&15]
//   C/D: lane,reg r -> D[row=q*4+r][col=lane&15]
// Swizzled LDS tile (128 rows x 32 shorts, no pad): 16B chunk slot c of row r
// holds logical chunk c ^ (r&3) (pre-swizzled global source, linear LDS dest).
// Wave-stage: wave wid covers rows [wid*16,wid*16+16), lane -> row lane>>2,
// chunk lane&3; b128 frag reads hit every bank exactly 8 words (minimum).

#define B_ 8
#define T_ 2048
#define D_ 1024
#define E_ 1024
#define PIT 56
#define NCH 8
#define CHR (T_ / NCH)   // 256 rows per stats chunk

typedef unsigned short u16;
typedef __attribute__((ext_vector_type(8))) short short8;
typedef __attribute__((ext_vector_type(4))) float floatx4;

__device__ __forceinline__ float b2f(u16 u) {
    unsigned v = ((unsigned)u) << 16;
    float f; __builtin_memcpy(&f, &v, 4); return f;
}
__device__ __forceinline__ u16 f2b(float f) {
    unsigned v; __builtin_memcpy(&v, &f, 4);
    v = (v + 0x7FFFu + ((v >> 16) & 1u)) >> 16;   // RNE
    return (u16)v;
}
__device__ __forceinline__ unsigned pkbf(float a, float b) {
    __hip_bfloat162 h = __float22bfloat162_rn(make_float2(a, b));
    unsigned u; __builtin_memcpy(&u, &h, 4); return u;
}

// async 16B global -> LDS (lds dest = wave-uniform base + lane*16)
__device__ __forceinline__ void gl2lds16(const u16* gp, u16* lp) {
    __builtin_amdgcn_global_load_lds(
        (const __attribute__((address_space(1))) void*)(gp),
        (__attribute__((address_space(3))) void*)(lp), 16, 0, 0);
}

// 8-wave (512-thread) stage of a 128-row x 32-short bf16 tile into swizzled
// LDS; 1 gl2lds per thread. Wave wid covers rows [wid*16, wid*16+16).
__device__ __forceinline__ void stage32(const u16* src, size_t srow, int kc,
                                        u16* lds, int wid, int lane)
{
    const int rl = lane >> 2, c = lane & 3;
    const int g = ((c ^ (rl & 3)) << 3);
    gl2lds16(src + (size_t)(wid * 16 + rl) * srow + kc + g, &lds[wid * 16 * 32]);
}

// one BK=32 MFMA step on a staged slot pair (8 mfma)
__device__ __forceinline__ void gemm_step32(const u16* As_, const u16* Bs_,
                                            int wr, int wc, int l15, int q,
                                            floatx4 (&acc)[2][4])
{
    const int sx = (q ^ (l15 & 3)) << 3;     // row&3 == l15&3 (wr,wc % 4 == 0)
    short8 a[2], b2[4];
#pragma unroll
    for (int i = 0; i < 2; i++)
        a[i] = *(const short8*)&As_[(wr + i * 16 + l15) * 32 + sx];
#pragma unroll
    for (int j = 0; j < 4; j++)
        b2[j] = *(const short8*)&Bs_[(wc + j * 16 + l15) * 32 + sx];
#pragma unroll
    for (int i = 0; i < 2; i++)
#pragma unroll
        for (int j = 0; j < 4; j++)
            acc[i][j] = __builtin_amdgcn_mfma_f32_16x16x32_bf16(a[i], b2[j], acc[i][j], 0, 0, 0);
}

// m/r stash inside S's strictly-upper dead zone (batch 0, rows 0..63, cols 1024+).
__device__ __forceinline__ float* mr_ptr(u16* S, int which, int b, int s) {
    const int row = which * 32 + b * 4 + (s >> 9);
    return (float*)(S + (size_t)row * T_ + 1024 + (s & 511) * 2);
}
// per-chunk partial (m,z): rows 64..319 (m) / 320..575 (z), cols 1024+ of batch 0.
__device__ __forceinline__ float* part_ptr(u16* S, int which, int c, int b, int s) {
    const int row = 64 + which * 256 + (c * 8 + b) * 4 + (s >> 9);
    return (float*)(S + (size_t)row * T_ + 1024 + (s & 511) * 2);
}

// ---------------- K0: WT[n][k] = bf16(W[k][n]) ----------------
__global__ __launch_bounds__(256) void k0_wt(const float* __restrict__ W,
                                             u16* __restrict__ WT)
{
    __shared__ float Ws[64 * 68];
    const int tid = threadIdx.x;
    const int k0 = blockIdx.x * 64, n0 = blockIdx.y * 64;
#pragma unroll
    for (int u = 0; u < 4; u++) {
        const int c = tid + 256 * u;
        const int row = c >> 4, c4 = c & 15;
        float4 v = *(const float4*)(W + (size_t)(k0 + row) * E_ + n0 + c4 * 4);
        *(float4*)&Ws[row * 68 + c4 * 4] = v;
    }
    __syncthreads();
#pragma unroll
    for (int u = 0; u < 2; u++) {
        const int c = tid + 256 * u;
        const int n = c >> 3, kc = c & 7;
        unsigned pk[4];
#pragma unroll
        for (int j = 0; j < 4; j++)
            pk[j] = pkbf(Ws[(kc * 8 + 2 * j) * 68 + n], Ws[(kc * 8 + 2 * j + 1) * 68 + n]);
        *(uint4*)(WT + (size_t)(n0 + n) * D_ + k0 + kc * 8) = make_uint4(pk[0], pk[1], pk[2], pk[3]);
    }
}

// ---------------- K00: xbf = bf16(x); optionally xT[b][d][t] = bf16(x[b][t][d]) ----------------
__global__ __launch_bounds__(256) void k00_xt(const float* __restrict__ x,
                                              u16* __restrict__ XT,
                                              u16* __restrict__ xbf,
                                              int do_xt)
{
    __shared__ float Xs[64 * 68];
    const int tid = threadIdx.x;
    const int s0 = blockIdx.x * 64, d0 = blockIdx.y * 64, b = blockIdx.z;
    const float* xb = x + (size_t)b * T_ * D_;
#pragma unroll
    for (int u = 0; u < 4; u++) {
        const int c = tid + 256 * u;
        const int row = c >> 4, c4 = c & 15;
        float4 v = *(const float4*)(xb + (size_t)(s0 + row) * D_ + d0 + c4 * 4);
        *(float4*)&Xs[row * 68 + c4 * 4] = v;
    }
    __syncthreads();
    // row-major bf16 copy (always)
#pragma unroll
    for (int u = 0; u < 2; u++) {
        const int c = tid + 256 * u;
        const int row = c >> 3, off = c & 7;
        unsigned pk[4];
#pragma unroll
        for (int j = 0; j < 4; j++)
            pk[j] = pkbf(Xs[row * 68 + off * 8 + 2 * j], Xs[row * 68 + off * 8 + 2 * j + 1]);
        *(uint4*)(xbf + ((size_t)(b * T_ + s0 + row)) * D_ + d0 + off * 8) =
            make_uint4(pk[0], pk[1], pk[2], pk[3]);
    }
    if (!do_xt) return;
    // transposed bf16 copy (fast path only)
#pragma unroll
    for (int u = 0; u < 2; u++) {
        const int c = tid + 256 * u;
        const int d = c >> 3, sc = c & 7;
        unsigned pk[4];
#pragma unroll
        for (int j = 0; j < 4; j++)
            pk[j] = pkbf(Xs[(sc * 8 + 2 * j) * 68 + d], Xs[(sc * 8 + 2 * j + 1) * 68 + d]);
        *(uint4*)(XT + ((size_t)(b * D_ + d0 + d)) * T_ + s0 + sc * 8) =
            make_uint4(pk[0], pk[1], pk[2], pk[3]);
    }
}

// ---------------- K1: y = bf16(xbf @ WT^T + b), 2-phase dbuf, BK=32 ----------------
__global__ __launch_bounds__(512, 8) void k1_proj(const u16* __restrict__ xbf,
                                                  const u16* __restrict__ WT,
                                                  const float* __restrict__ bias,
                                                  u16* __restrict__ y)
{
    __shared__ u16 As[2][128 * 32];
    __shared__ u16 Bs[2][128 * 32];
    const int tid = threadIdx.x;
    const int lane = tid & 63, wid = tid >> 6;
    const int wr = (wid >> 1) * 32, wc = (wid & 1) * 64;
    const int l15 = lane & 15, q = lane >> 4;
    // XCD-chunked swizzle: XCD c owns m-tiles [16c,16c+16) (A panel ~4MB -> L2-hot)
    const int lin = blockIdx.y * 8 + blockIdx.x;      // 1024 blocks, %8==0
    const int v = (lin & 7) * 128 + (lin >> 3);
    const int n0 = (v & 7) * 128, m0 = (v >> 3) * 128;
    const u16* Ab = xbf + (size_t)m0 * D_;
    const u16* Bb = WT + (size_t)n0 * D_;

    floatx4 acc[2][4];
#pragma unroll
    for (int i = 0; i < 2; i++)
#pragma unroll
        for (int j = 0; j < 4; j++) acc[i][j] = (floatx4){0.f, 0.f, 0.f, 0.f};

    stage32(Ab, D_, 0, As[0], wid, lane);
    stage32(Bb, D_, 0, Bs[0], wid, lane);
    __syncthreads();
    int cur = 0;
    for (int t = 0; t < 32; t++) {
        if (t + 1 < 32) {
            stage32(Ab, D_, (t + 1) * 32, As[cur ^ 1], wid, lane);
            stage32(Bb, D_, (t + 1) * 32, Bs[cur ^ 1], wid, lane);
        }
        gemm_step32(As[cur], Bs[cur], wr, wc, l15, q, acc);
        __syncthreads();
        cur ^= 1;
    }
    float bv[4];
#pragma unroll
    for (int j = 0; j < 4; j++) bv[j] = bias[n0 + wc + j * 16 + l15];
#pragma unroll
    for (int i = 0; i < 2; i++)
#pragma unroll
        for (int j = 0; j < 4; j++)
#pragma unroll
            for (int r = 0; r < 4; r++) {
                const int gm = m0 + wr + i * 16 + q * 4 + r;
                const int gn = n0 + wc + j * 16 + l15;
                y[(size_t)gm * E_ + gn] = f2b(acc[i][j][r] + bv[j]);
            }
}

// ---------------- K2: S tiles, 2-phase dbuf, BK=32, batch->XCD ----------------
__global__ __launch_bounds__(512, 8) void k2_score(const u16* __restrict__ y,
                                                   u16* __restrict__ S)
{
    __shared__ u16 As[2][128 * 32];
    __shared__ u16 Bs[2][128 * 32];
    const int tid = threadIdx.x;
    const int lane = tid & 63, wid = tid >> 6;
    const int wr = (wid >> 1) * 32, wc = (wid & 1) * 64;
    const int l15 = lane & 15, q = lane >> 4;
    // batch->XCD swizzle: flat grid of 1088 = 136 tiles x 8 batches.
    // b = lin&7 pins batch b to XCD b (round-robin dispatch); y[b] = 4MiB = L2.
    const int lin = blockIdx.x;
    const int b = lin & 7;
    int idx = lin >> 3;                  // 0..135 triangular tile id
    int it = 0, base = 0;
    while (base + it + 1 <= idx) { base += it + 1; it++; }
    const int js = idx - base;
    const int t0 = it * 128, s0 = js * 128;
    const u16* yb = y + (size_t)b * T_ * E_;
    const u16* Ab = yb + (size_t)t0 * E_;
    const u16* Bb = yb + (size_t)s0 * E_;

    floatx4 acc[2][4];
#pragma unroll
    for (int i = 0; i < 2; i++)
#pragma unroll
        for (int j = 0; j < 4; j++) acc[i][j] = (floatx4){0.f, 0.f, 0.f, 0.f};

    stage32(Ab, E_, 0, As[0], wid, lane);
    stage32(Bb, E_, 0, Bs[0], wid, lane);
    __syncthreads();
    int cur = 0;
    for (int t = 0; t < 32; t++) {
        if (t + 1 < 32) {
            stage32(Ab, E_, (t + 1) * 32, As[cur ^ 1], wid, lane);
            stage32(Bb, E_, (t + 1) * 32, Bs[cur ^ 1], wid, lane);
        }
        gemm_step32(As[cur], Bs[cur], wr, wc, l15, q, acc);
        __syncthreads();
        cur ^= 1;
    }
#pragma unroll
    for (int i = 0; i < 2; i++)
#pragma unroll
        for (int j = 0; j < 4; j++)
#pragma unroll
            for (int r = 0; r < 4; r++) {
                const int t = t0 + wr + i * 16 + q * 4 + r;
                const int s = s0 + wc + j * 16 + l15;
                u16 o = (t < s) ? (u16)0xFF7F : f2b(acc[i][j][r] * 0.03125f);
                S[((size_t)(b * T_ + t)) * T_ + s] = o;
            }
}

// ---------------- K2b_part: per-(chunk,col) partial (m, z) over t in chunk ----------------
__global__ __launch_bounds__(256) void k2b_part(u16* __restrict__ S)
{
    __shared__ u16 St[CHR * 64];          // 32 KiB
    __shared__ float sm[4][64], sz[4][64];
    const int tid = threadIdx.x;
    const int lane = tid & 63, w = tid >> 6;
    const int s0 = blockIdx.x * 64;
    const int c  = blockIdx.y;
    const int b  = blockIdx.z;
    const int tb = max(c * CHR, s0);      // causal: only t >= s0 (64-aligned)
    const int te = (c + 1) * CHR;
    if (tb >= te) return;                 // chunk entirely above this column strip
    const int R = te - tb;                // multiple of 64
    const u16* Sb = S + (size_t)b * T_ * T_;
    // stage R x 64 tile (rows are 128B contiguous; 32 rows per 256-thread round)
    for (int r0 = 0; r0 < R; r0 += 32) {
        const int row = r0 + (tid >> 3), off = tid & 7;
        *(uint4*)&St[row * 64 + off * 8] =
            *(const uint4*)(Sb + (size_t)(tb + row) * T_ + s0 + off * 8);
    }
    __syncthreads();
    // thread (w,lane): rows [w*64, w*64+64) of column lane; two-pass, 4 accums.
    const int rb = w * 64;
    float m4[4] = {-3e38f, -3e38f, -3e38f, -3e38f};
    float z4[4] = {0.f, 0.f, 0.f, 0.f};
    float mt = -3e38f;
    if (rb < R) {
#pragma unroll 4
        for (int i = 0; i < 64; i += 4)
#pragma unroll
            for (int j = 0; j < 4; j++)
                m4[j] = fmaxf(m4[j], b2f(St[(rb + i + j) * 64 + lane]));
        mt = fmaxf(fmaxf(m4[0], m4[1]), fmaxf(m4[2], m4[3]));
#pragma unroll 4
        for (int i = 0; i < 64; i += 4)
#pragma unroll
            for (int j = 0; j < 4; j++)
                z4[j] += __expf(b2f(St[(rb + i + j) * 64 + lane]) - mt);
    }
    sm[w][lane] = mt;
    sz[w][lane] = (z4[0] + z4[1]) + (z4[2] + z4[3]);
    __syncthreads();
    if (tid < 64) {
        float mm = sm[0][tid];
#pragma unroll
        for (int rr = 1; rr < 4; rr++) mm = fmaxf(mm, sm[rr][tid]);
        float zz = 0.f;
#pragma unroll
        for (int rr = 0; rr < 4; rr++) zz += sz[rr][tid] * __expf(sm[rr][tid] - mm);
        *part_ptr(S, 0, c, b, s0 + tid) = mm;
        *part_ptr(S, 1, c, b, s0 + tid) = zz;
    }
}

// ---------------- K2c_comb: combine <=8 chunk partials -> (m, 1/z) stash ----------------
__global__ __launch_bounds__(256) void k2c_comb(u16* __restrict__ S)
{
    const int s = blockIdx.x * 256 + threadIdx.x;
    const int b = blockIdx.y;
    float M = -3e38f, Z = 0.f;
    for (int c = s >> 8; c < NCH; c++) {      // chunks below s0 were never written
        const float mc = *part_ptr(S, 0, c, b, s);
        const float zc = *part_ptr(S, 1, c, b, s);
        if (mc > M) { Z = Z * __expf(M - mc) + zc; M = mc; }
        else        { Z += zc * __expf(mc - M); }
    }
    *mr_ptr(S, 0, b, s) = M;
    *mr_ptr(S, 1, b, s) = 1.0f / Z;
}

// ---------------- K3: P = exp(S - m_s) * r_s  (in place, causal-restricted) ----------------
__global__ __launch_bounds__(256) void k3_pnorm(u16* __restrict__ S)
{
    const int row = blockIdx.x;          // b*T + t
    const int b = row >> 11;
    const int t = row & (T_ - 1);
    const int sEnd = ((t >> 7) + 1) << 7;
    const int s0 = threadIdx.x * 8;
    if (s0 >= sEnd) return;
    u16* Sp = S + (size_t)row * T_ + s0;
    const float* mp = mr_ptr(S, 0, b, s0);
    const float* rp = mr_ptr(S, 1, b, s0);
    float mv[8], rv[8];
    *(float4*)&mv[0] = *(const float4*)mp;
    *(float4*)&mv[4] = *((const float4*)mp + 1);
    *(float4*)&rv[0] = *(const float4*)rp;
    *(float4*)&rv[4] = *((const float4*)rp + 1);
    ushort4 v0 = *(ushort4*)Sp;
    ushort4 v1 = *(ushort4*)(Sp + 4);
    u16 vv[8] = { v0.x, v0.y, v0.z, v0.w, v1.x, v1.y, v1.z, v1.w };
    u16 ov[8];
#pragma unroll
    for (int i = 0; i < 8; i++) {
        const int s = s0 + i;
        float p = 0.f;
        if (s <= t) p = __expf(b2f(vv[i]) - mv[i]) * rv[i];
        ov[i] = f2b(p);
    }
    *(ushort4*)Sp       = make_ushort4(ov[0], ov[1], ov[2], ov[3]);
    *(ushort4*)(Sp + 4) = make_ushort4(ov[4], ov[5], ov[6], ov[7]);
}

// ---------------- K4 fast: out = P @ xT^T, 2-phase dbuf, BK=32, batch->XCD ----------------
__global__ __launch_bounds__(512, 8) void k4_fast(const u16* __restrict__ P,
                                                  const u16* __restrict__ XT,
                                                  float* __restrict__ out)
{
    __shared__ u16 As[2][128 * 32];
    __shared__ u16 Bs[2][128 * 32];
    const int tid = threadIdx.x;
    const int lane = tid & 63, wid = tid >> 6;
    const int wr = (wid >> 1) * 32, wc = (wid & 1) * 64;
    const int l15 = lane & 15, q = lane >> 4;
    // batch->XCD swizzle: flat grid of 1024 = 8 d-blk x 16 it x 8 batches.
    // b = lin&7 pins batch b to XCD b; XT[b] = 4MiB = one XCD's L2.
    const int lin = blockIdx.x;
    const int b = lin & 7;
    const int r8 = lin >> 3;                     // 0..127
    const int d0 = (r8 & 7) * 128;
    const int it = (T_ / 128 - 1) - (r8 >> 3);   // heavy tiles first
    const int t0 = it * 128;
    const u16* Pb = P + (size_t)b * T_ * T_ + (size_t)t0 * T_;
    const u16* Xb = XT + (size_t)(b * D_ + d0) * T_;

    floatx4 acc[2][4];
#pragma unroll
    for (int i = 0; i < 2; i++)
#pragma unroll
        for (int j = 0; j < 4; j++) acc[i][j] = (floatx4){0.f, 0.f, 0.f, 0.f};

    const int nt = (it + 1) * 4;      // K-steps of 32 up to t0+128 (>= 4)
    stage32(Pb, T_, 0, As[0], wid, lane);
    stage32(Xb, T_, 0, Bs[0], wid, lane);
    __syncthreads();
    int cur = 0;
    for (int t = 0; t < nt; t++) {
        if (t + 1 < nt) {
            stage32(Pb, T_, (t + 1) * 32, As[cur ^ 1], wid, lane);
            stage32(Xb, T_, (t + 1) * 32, Bs[cur ^ 1], wid, lane);
        }
        gemm_step32(As[cur], Bs[cur], wr, wc, l15, q, acc);
        __syncthreads();
        cur ^= 1;
    }
#pragma unroll
    for (int i = 0; i < 2; i++)
#pragma unroll
        for (int j = 0; j < 4; j++)
#pragma unroll
            for (int r = 0; r < 4; r++) {
                const int gt = t0 + wr + i * 16 + q * 4 + r;
                const int gd = d0 + wc + j * 16 + l15;
                out[(size_t)(b * T_ + gt) * D_ + gd] = acc[i][j][r];
            }
}

// ---------------- K4 fallback (round-4): scalar-gather B-stage ----------------
__global__ __launch_bounds__(256) void k4_fb(const u16* __restrict__ P,
                                             const float* __restrict__ x,
                                             float* __restrict__ out)
{
    __shared__ u16 As[128 * PIT];
    __shared__ u16 Bs[128 * PIT];
    const int tid = threadIdx.x;
    const int lane = tid & 63, wid = tid >> 6;
    const int wr = (wid >> 1) * 64, wc = (wid & 1) * 64;
    const int l15 = lane & 15, q = lane >> 4;
    const int it = (T_ / 128 - 1) - blockIdx.y;
    const int t0 = it * 128;
    const int d0 = blockIdx.x * 128;
    const int b = blockIdx.z;
    const u16* Pb = P + (size_t)b * T_ * T_;
    const float* xb = x + (size_t)b * T_ * D_;
    const int gn = tid & 127;
    const int kh0 = (tid >> 7) * 2;

    floatx4 acc[4][4];
#pragma unroll
    for (int i = 0; i < 4; i++)
#pragma unroll
        for (int j = 0; j < 4; j++) acc[i][j] = (floatx4){0.f, 0.f, 0.f, 0.f};

    const int kend = t0 + 128;
    for (int k0 = 0; k0 < kend; k0 += 32) {
        __syncthreads();
#pragma unroll
        for (int u = 0; u < 2; u++) {
            const int c = tid * 2 + u;
            const int row = c >> 2, off = c & 3;
            *(uint4*)&As[row * PIT + off * 8] =
                *(const uint4*)(Pb + (size_t)(t0 + row) * T_ + k0 + off * 8);
        }
#pragma unroll
        for (int u = 0; u < 2; u++) {
            const int kh = kh0 + u;
            float f[8];
#pragma unroll
            for (int j = 0; j < 8; j++)
                f[j] = xb[(size_t)(k0 + kh * 8 + j) * D_ + d0 + gn];
            uint4 pk = make_uint4(pkbf(f[0], f[1]), pkbf(f[2], f[3]),
                                  pkbf(f[4], f[5]), pkbf(f[6], f[7]));
            *(uint4*)&Bs[gn * PIT + kh * 8] = pk;
        }
        __syncthreads();
        short8 a[4], b2[4];
#pragma unroll
        for (int i = 0; i < 4; i++) a[i] = *(const short8*)&As[(wr + i * 16 + l15) * PIT + q * 8];
#pragma unroll
        for (int j = 0; j < 4; j++) b2[j] = *(const short8*)&Bs[(wc + j * 16 + l15) * PIT + q * 8];
#pragma unroll
        for (int i = 0; i < 4; i++)
#pragma unroll
            for (int j = 0; j < 4; j++)
                acc[i][j] = __builtin_amdgcn_mfma_f32_16x16x32_bf16(a[i], b2[j], acc[i][j], 0, 0, 0);
    }
#pragma unroll
    for (int i = 0; i < 4; i++)
#pragma unroll
        for (int j = 0; j < 4; j++)
#pragma unroll
            for (int r = 0; r < 4; r++) {
                const int gt = t0 + wr + i * 16 + q * 4 + r;
                const int gd = d0 + wc + j * 16 + l15;
                out[(size_t)(b * T_ + gt) * D_ + gd] = acc[i][j][r];
            }
}

extern "C" void kernel_launch(void* const* d_in, const int* in_sizes, int n_in,
                              void* d_out, int out_size, void* d_ws, size_t ws_size,
                              hipStream_t stream)
{
    const float* x    = (const float*)d_in[0];
    const float* W    = (const float*)d_in[1];
    const float* bias = (const float*)d_in[2];
    float* outf = (float*)d_out;
    u16*   y    = (u16*)d_out;                  // bf16, first 32 MiB of d_out
    u16*   WT   = y + ((size_t)1 << 24);        // 32MiB..34MiB of d_out (dead before k4)
    u16*   S    = (u16*)d_ws;                   // 64 MiB (m/r + partials in dead zone)
    u16*   xbf  = S;                            // bf16 x, ws[0:32MiB] (dead before k2)
    u16*   XT   = S + ((size_t)1 << 25);        // ws+64MiB..+96MiB (fast path only)
    const bool fast = ws_size >= ((size_t)96 << 20);

    dim3 g0(D_ / 64, E_ / 64);            // (16,16)
    k0_wt<<<g0, 256, 0, stream>>>(W, WT);

    dim3 g00(T_ / 64, D_ / 64, B_);       // (32,16,8)
    k00_xt<<<g00, 256, 0, stream>>>(x, XT, xbf, fast ? 1 : 0);

    dim3 g1(E_ / 128, (B_ * T_) / 128);   // (8, 128)
    k1_proj<<<g1, 512, 0, stream>>>(xbf, WT, bias, y);

    dim3 g2(136 * B_);                    // flat, batch->XCD
    k2_score<<<g2, 512, 0, stream>>>(y, S);

    dim3 gp(T_ / 64, NCH, B_);            // (32, 8, 8) = 2048 blocks
    k2b_part<<<gp, 256, 0, stream>>>(S);

    dim3 gc(T_ / 256, B_);                // (8, 8)
    k2c_comb<<<gc, 256, 0, stream>>>(S);

    dim3 g3(B_ * T_);
    k3_pnorm<<<g3, 256, 0, stream>>>(S);

    dim3 g4((D_ / 128) * (T_ / 128) * B_);   // flat 1024, batch->XCD
    if (fast) k4_fast<<<g4, 512, 0, stream>>>(S, XT, outf);
    else {
        dim3 g4b(D_ / 128, T_ / 128, B_);
        k4_fb<<<g4b, 256, 0, stream>>>(S, x, outf);
    }
}

// Round 8
// 291.559 us; speedup vs baseline: 1.1522x; 1.1522x over previous
//
#include <hip/hip_runtime.h>
#include <hip/hip_bf16.h>

// B=8, T=2048, D=1024, E=1024
//   k0 : WT = bf16(W^T)                 -> d_out[32MiB..34MiB] (dead before k4)
//   k00: xbf = bf16(x) [B][T][D]        -> d_ws[0:32MiB]   (dead before k2 writes S)
//        xT  = bf16(x^T) [B][D][T]      -> d_ws[64MiB..96MiB] (only if ws >= 96MiB)
//   k1 : y = bf16(xbf@WT^T + b)         -> d_out[0:32MiB]  (2-phase dbuf MFMA, BK=64)
//   k2 : S[b,t,s] = bf16(y_t.y_s/32)    -> d_ws, lower-triangle tiles (BK=64)
//        + fused per-(tile,column) softmax partials (m,z) -> batch dead zone
//   k2c: combine <=16 it-partials/column -> m_s, r_s=1/z_s stash (rows 0..63)
//   k3 : P = exp(S-m_s)*r_s in place    (causal-restricted)
//   k4 : out = P @ x  fp32  — fast path: 2-phase dbuf from P and xT.
//
// Round-8: REVERT round-7 BK=32 (k2 54->74us: MfmaUtil 26.6->18.9, 6.7M bank
//   conflicts, 2x barriers — BK=64 128^2 2-phase is the verified optimum on
//   pipeline-depth/occupancy/BK axes). NEW: k2b_part fused into k2's epilogue
//   (tile is already in registers; stats on the same bf16-rounded values),
//   partials (m,z) per (it-tile, column) as float2 in batch-b dead zone rows
//   64..191 cols 1024+ (k2 writes cols<640 for rows<640; k4 reads cols<
//   ((row>>7)+1)*128 <= 256 for rows<192; k3 same bound => region is dead).
//   Deletes k2b_part kernel + its 34MB S re-read.
//
// MFMA 16x16x32 bf16 frag layouts (HW-verified):
//   A: lane holds A[m=lane&15][k=q*8+j]; B: B[k=q*8+j][n=lane&15]
//   C/D: lane,reg r -> D[row=q*4+r][col=lane&15]
// Swizzled LDS tile (128 rows x 64 shorts, no pad): 16B chunk slot c of row r
// holds logical chunk c ^ (r&7) (pre-swizzled global source, linear LDS dest).

#define B_ 8
#define T_ 2048
#define D_ 1024
#define E_ 1024
#define PIT 56

typedef unsigned short u16;
typedef __attribute__((ext_vector_type(8))) short short8;
typedef __attribute__((ext_vector_type(4))) float floatx4;

__device__ __forceinline__ float b2f(u16 u) {
    unsigned v = ((unsigned)u) << 16;
    float f; __builtin_memcpy(&f, &v, 4); return f;
}
__device__ __forceinline__ u16 f2b(float f) {
    unsigned v; __builtin_memcpy(&v, &f, 4);
    v = (v + 0x7FFFu + ((v >> 16) & 1u)) >> 16;   // RNE
    return (u16)v;
}
__device__ __forceinline__ unsigned pkbf(float a, float b) {
    __hip_bfloat162 h = __float22bfloat162_rn(make_float2(a, b));
    unsigned u; __builtin_memcpy(&u, &h, 4); return u;
}

// async 16B global -> LDS (lds dest = wave-uniform base + lane*16)
__device__ __forceinline__ void gl2lds16(const u16* gp, u16* lp) {
    __builtin_amdgcn_global_load_lds(
        (const __attribute__((address_space(1))) void*)(gp),
        (__attribute__((address_space(3))) void*)(lp), 16, 0, 0);
}

// 8-wave (512-thread) stage of a 128-row x 64-short bf16 tile into swizzled LDS.
__device__ __forceinline__ void stage8(const u16* src, size_t srow, int kc,
                                       u16* lds, int wid, int lane)
{
    const int rl = lane >> 3, c = lane & 7;
    const int g = ((c ^ rl) << 3);
#pragma unroll
    for (int cc = 0; cc < 2; cc++) {
        const int r = cc * 64 + wid * 8;
        gl2lds16(src + (size_t)(r + rl) * srow + kc + g, &lds[r * 64]);
    }
}

// one BK=64 MFMA step on a staged slot pair (16 mfma)
__device__ __forceinline__ void gemm_step(const u16* As_, const u16* Bs_,
                                          int wr, int wc, int l15, int q, int sw,
                                          floatx4 (&acc)[2][4])
{
#pragma unroll
    for (int h = 0; h < 2; h++) {
        short8 a[2], b2[4];
#pragma unroll
        for (int i = 0; i < 2; i++)
            a[i] = *(const short8*)&As_[(wr + i * 16 + l15) * 64 + (((h * 4 + q) ^ sw) << 3)];
#pragma unroll
        for (int j = 0; j < 4; j++)
            b2[j] = *(const short8*)&Bs_[(wc + j * 16 + l15) * 64 + (((h * 4 + q) ^ sw) << 3)];
#pragma unroll
        for (int i = 0; i < 2; i++)
#pragma unroll
            for (int j = 0; j < 4; j++)
                acc[i][j] = __builtin_amdgcn_mfma_f32_16x16x32_bf16(a[i], b2[j], acc[i][j], 0, 0, 0);
    }
}

// m/r stash inside S's strictly-upper dead zone (batch 0, rows 0..63, cols 1024+).
__device__ __forceinline__ float* mr_ptr(u16* S, int which, int b, int s) {
    const int row = which * 32 + b * 4 + (s >> 9);
    return (float*)(S + (size_t)row * T_ + 1024 + (s & 511) * 2);
}
// per-(it-tile, column) partial (m,z) float2 in batch b's dead zone,
// rows 64..191, cols 1024+ (dead vs k2 writes / k3 / k4 reads for rows<192).
__device__ __forceinline__ float2* part2_ptr(u16* S, int it, int b, int s) {
    const int row = 64 + it * 8 + (s >> 8);
    return (float2*)(S + (size_t)b * T_ * T_ + (size_t)row * T_ + 1024 + (s & 255) * 4);
}

// ---------------- K0: WT[n][k] = bf16(W[k][n]) ----------------
__global__ __launch_bounds__(256) void k0_wt(const float* __restrict__ W,
                                             u16* __restrict__ WT)
{
    __shared__ float Ws[64 * 68];
    const int tid = threadIdx.x;
    const int k0 = blockIdx.x * 64, n0 = blockIdx.y * 64;
#pragma unroll
    for (int u = 0; u < 4; u++) {
        const int c = tid + 256 * u;
        const int row = c >> 4, c4 = c & 15;
        float4 v = *(const float4*)(W + (size_t)(k0 + row) * E_ + n0 + c4 * 4);
        *(float4*)&Ws[row * 68 + c4 * 4] = v;
    }
    __syncthreads();
#pragma unroll
    for (int u = 0; u < 2; u++) {
        const int c = tid + 256 * u;
        const int n = c >> 3, kc = c & 7;
        unsigned pk[4];
#pragma unroll
        for (int j = 0; j < 4; j++)
            pk[j] = pkbf(Ws[(kc * 8 + 2 * j) * 68 + n], Ws[(kc * 8 + 2 * j + 1) * 68 + n]);
        *(uint4*)(WT + (size_t)(n0 + n) * D_ + k0 + kc * 8) = make_uint4(pk[0], pk[1], pk[2], pk[3]);
    }
}

// ---------------- K00: xbf = bf16(x); optionally xT[b][d][t] = bf16(x[b][t][d]) ----------------
__global__ __launch_bounds__(256) void k00_xt(const float* __restrict__ x,
                                              u16* __restrict__ XT,
                                              u16* __restrict__ xbf,
                                              int do_xt)
{
    __shared__ float Xs[64 * 68];
    const int tid = threadIdx.x;
    const int s0 = blockIdx.x * 64, d0 = blockIdx.y * 64, b = blockIdx.z;
    const float* xb = x + (size_t)b * T_ * D_;
#pragma unroll
    for (int u = 0; u < 4; u++) {
        const int c = tid + 256 * u;
        const int row = c >> 4, c4 = c & 15;
        float4 v = *(const float4*)(xb + (size_t)(s0 + row) * D_ + d0 + c4 * 4);
        *(float4*)&Xs[row * 68 + c4 * 4] = v;
    }
    __syncthreads();
    // row-major bf16 copy (always)
#pragma unroll
    for (int u = 0; u < 2; u++) {
        const int c = tid + 256 * u;
        const int row = c >> 3, off = c & 7;
        unsigned pk[4];
#pragma unroll
        for (int j = 0; j < 4; j++)
            pk[j] = pkbf(Xs[row * 68 + off * 8 + 2 * j], Xs[row * 68 + off * 8 + 2 * j + 1]);
        *(uint4*)(xbf + ((size_t)(b * T_ + s0 + row)) * D_ + d0 + off * 8) =
            make_uint4(pk[0], pk[1], pk[2], pk[3]);
    }
    if (!do_xt) return;
    // transposed bf16 copy (fast path only)
#pragma unroll
    for (int u = 0; u < 2; u++) {
        const int c = tid + 256 * u;
        const int d = c >> 3, sc = c & 7;
        unsigned pk[4];
#pragma unroll
        for (int j = 0; j < 4; j++)
            pk[j] = pkbf(Xs[(sc * 8 + 2 * j) * 68 + d], Xs[(sc * 8 + 2 * j + 1) * 68 + d]);
        *(uint4*)(XT + ((size_t)(b * D_ + d0 + d)) * T_ + s0 + sc * 8) =
            make_uint4(pk[0], pk[1], pk[2], pk[3]);
    }
}

// ---------------- K1: y = bf16(xbf @ WT^T + b), 2-phase dbuf, BK=64 ----------------
__global__ __launch_bounds__(512, 4) void k1_proj(const u16* __restrict__ xbf,
                                                  const u16* __restrict__ WT,
                                                  const float* __restrict__ bias,
                                                  u16* __restrict__ y)
{
    __shared__ u16 As[2][128 * 64];
    __shared__ u16 Bs[2][128 * 64];
    const int tid = threadIdx.x;
    const int lane = tid & 63, wid = tid >> 6;
    const int wr = (wid >> 1) * 32, wc = (wid & 1) * 64;
    const int l15 = lane & 15, q = lane >> 4;
    const int sw = l15 & 7;
    // XCD-chunked swizzle: XCD c owns m-tiles [16c,16c+16) (A panel ~4MB -> L2-hot)
    const int lin = blockIdx.y * 8 + blockIdx.x;      // 1024 blocks, %8==0
    const int v = (lin & 7) * 128 + (lin >> 3);
    const int n0 = (v & 7) * 128, m0 = (v >> 3) * 128;
    const u16* Ab = xbf + (size_t)m0 * D_;
    const u16* Bb = WT + (size_t)n0 * D_;

    floatx4 acc[2][4];
#pragma unroll
    for (int i = 0; i < 2; i++)
#pragma unroll
        for (int j = 0; j < 4; j++) acc[i][j] = (floatx4){0.f, 0.f, 0.f, 0.f};

    stage8(Ab, D_, 0, As[0], wid, lane);
    stage8(Bb, D_, 0, Bs[0], wid, lane);
    __syncthreads();
    int cur = 0;
    for (int t = 0; t < 16; t++) {
        if (t + 1 < 16) {
            stage8(Ab, D_, (t + 1) * 64, As[cur ^ 1], wid, lane);
            stage8(Bb, D_, (t + 1) * 64, Bs[cur ^ 1], wid, lane);
        }
        gemm_step(As[cur], Bs[cur], wr, wc, l15, q, sw, acc);
        __syncthreads();
        cur ^= 1;
    }
    float bv[4];
#pragma unroll
    for (int j = 0; j < 4; j++) bv[j] = bias[n0 + wc + j * 16 + l15];
#pragma unroll
    for (int i = 0; i < 2; i++)
#pragma unroll
        for (int j = 0; j < 4; j++)
#pragma unroll
            for (int r = 0; r < 4; r++) {
                const int gm = m0 + wr + i * 16 + q * 4 + r;
                const int gn = n0 + wc + j * 16 + l15;
                y[(size_t)gm * E_ + gn] = f2b(acc[i][j][r] + bv[j]);
            }
}

// ---------------- K2: S tiles + fused column-stat partials, BK=64, batch->XCD ----------------
__global__ __launch_bounds__(512, 4) void k2_score(const u16* __restrict__ y,
                                                   u16* __restrict__ S)
{
    __shared__ u16 As[2][128 * 64];
    __shared__ u16 Bs[2][128 * 64];
    __shared__ float smf[8][64], smz[8][64];
    const int tid = threadIdx.x;
    const int lane = tid & 63, wid = tid >> 6;
    const int wr = (wid >> 1) * 32, wc = (wid & 1) * 64;
    const int l15 = lane & 15, q = lane >> 4;
    const int sw = l15 & 7;
    // batch->XCD swizzle: flat grid of 1088 = 136 tiles x 8 batches.
    // b = lin&7 pins batch b to XCD b (round-robin dispatch); y[b] = 4MiB = L2.
    const int lin = blockIdx.x;
    const int b = lin & 7;
    int idx = lin >> 3;                  // 0..135 triangular tile id
    int it = 0, base = 0;
    while (base + it + 1 <= idx) { base += it + 1; it++; }
    const int js = idx - base;
    const int t0 = it * 128, s0 = js * 128;
    const u16* yb = y + (size_t)b * T_ * E_;
    const u16* Ab = yb + (size_t)t0 * E_;
    const u16* Bb = yb + (size_t)s0 * E_;

    floatx4 acc[2][4];
#pragma unroll
    for (int i = 0; i < 2; i++)
#pragma unroll
        for (int j = 0; j < 4; j++) acc[i][j] = (floatx4){0.f, 0.f, 0.f, 0.f};

    stage8(Ab, E_, 0, As[0], wid, lane);
    stage8(Bb, E_, 0, Bs[0], wid, lane);
    __syncthreads();
    int cur = 0;
    for (int t = 0; t < 16; t++) {
        if (t + 1 < 16) {
            stage8(Ab, E_, (t + 1) * 64, As[cur ^ 1], wid, lane);
            stage8(Bb, E_, (t + 1) * 64, Bs[cur ^ 1], wid, lane);
        }
        gemm_step(As[cur], Bs[cur], wr, wc, l15, q, sw, acc);
        __syncthreads();
        cur ^= 1;
    }
    // ---- epilogue: write tile + per-thread (m,z) on the bf16-rounded values ----
    float pm[4] = {-1e38f, -1e38f, -1e38f, -1e38f};
    float pz[4] = {0.f, 0.f, 0.f, 0.f};
    u16 ov[2][4][4];
#pragma unroll
    for (int i = 0; i < 2; i++)
#pragma unroll
        for (int j = 0; j < 4; j++)
#pragma unroll
            for (int r = 0; r < 4; r++) {
                const int t = t0 + wr + i * 16 + q * 4 + r;
                const int s = s0 + wc + j * 16 + l15;
                u16 o = (t < s) ? (u16)0xFF7F : f2b(acc[i][j][r] * 0.03125f);
                S[((size_t)(b * T_ + t)) * T_ + s] = o;
                ov[i][j][r] = o;
                if (t >= s) pm[j] = fmaxf(pm[j], b2f(o));
            }
#pragma unroll
    for (int i = 0; i < 2; i++)
#pragma unroll
        for (int j = 0; j < 4; j++)
#pragma unroll
            for (int r = 0; r < 4; r++) {
                const int t = t0 + wr + i * 16 + q * 4 + r;
                const int s = s0 + wc + j * 16 + l15;
                const float ez = __expf(b2f(ov[i][j][r]) - pm[j]);
                pz[j] += (t >= s) ? ez : 0.f;
            }
    // merge across the 4 q-lanes sharing each column (lane ^16, ^32)
#pragma unroll
    for (int j = 0; j < 4; j++) {
#pragma unroll
        for (int d = 16; d < 64; d <<= 1) {
            const float om = __shfl_xor(pm[j], d);
            const float oz = __shfl_xor(pz[j], d);
            const float nm = fmaxf(pm[j], om);
            pz[j] = pz[j] * __expf(pm[j] - nm) + oz * __expf(om - nm);
            pm[j] = nm;
        }
    }
    if (q == 0)
#pragma unroll
        for (int j = 0; j < 4; j++) {
            smf[wid][j * 16 + l15] = pm[j];
            smz[wid][j * 16 + l15] = pz[j];
        }
    __syncthreads();
    if (tid < 128) {   // one thread per tile column: merge the 4 row-wave groups
        const int half = tid >> 6, cidx = tid & 63;
        float M = -1e38f, Z = 0.f;
#pragma unroll
        for (int g = 0; g < 4; g++) {
            const float m2 = smf[g * 2 + half][cidx];
            const float z2 = smz[g * 2 + half][cidx];
            const float nm = fmaxf(M, m2);
            Z = Z * __expf(M - nm) + z2 * __expf(m2 - nm);
            M = nm;
        }
        *part2_ptr(S, it, b, s0 + half * 64 + cidx) = make_float2(M, Z);
    }
}

// ---------------- K2c_comb: combine <=16 it-partials -> (m, 1/z) stash ----------------
__global__ __launch_bounds__(256) void k2c_comb(u16* __restrict__ S)
{
    const int s = blockIdx.x * 256 + threadIdx.x;
    const int b = blockIdx.y;
    float M = -1e38f, Z = 0.f;
    for (int it = s >> 7; it < 16; it++) {   // tiles above the diagonal never wrote
        const float2 p = *part2_ptr(S, it, b, s);
        const float nm = fmaxf(M, p.x);
        Z = Z * __expf(M - nm) + p.y * __expf(p.x - nm);
        M = nm;
    }
    *mr_ptr(S, 0, b, s) = M;
    *mr_ptr(S, 1, b, s) = 1.0f / Z;
}

// ---------------- K3: P = exp(S - m_s) * r_s  (in place, causal-restricted) ----------------
__global__ __launch_bounds__(256) void k3_pnorm(u16* __restrict__ S)
{
    const int row = blockIdx.x;          // b*T + t
    const int b = row >> 11;
    const int t = row & (T_ - 1);
    const int sEnd = ((t >> 7) + 1) << 7;
    const int s0 = threadIdx.x * 8;
    if (s0 >= sEnd) return;
    u16* Sp = S + (size_t)row * T_ + s0;
    const float* mp = mr_ptr(S, 0, b, s0);
    const float* rp = mr_ptr(S, 1, b, s0);
    float mv[8], rv[8];
    *(float4*)&mv[0] = *(const float4*)mp;
    *(float4*)&mv[4] = *((const float4*)mp + 1);
    *(float4*)&rv[0] = *(const float4*)rp;
    *(float4*)&rv[4] = *((const float4*)rp + 1);
    ushort4 v0 = *(ushort4*)Sp;
    ushort4 v1 = *(ushort4*)(Sp + 4);
    u16 vv[8] = { v0.x, v0.y, v0.z, v0.w, v1.x, v1.y, v1.z, v1.w };
    u16 ov[8];
#pragma unroll
    for (int i = 0; i < 8; i++) {
        const int s = s0 + i;
        float p = 0.f;
        if (s <= t) p = __expf(b2f(vv[i]) - mv[i]) * rv[i];
        ov[i] = f2b(p);
    }
    *(ushort4*)Sp       = make_ushort4(ov[0], ov[1], ov[2], ov[3]);
    *(ushort4*)(Sp + 4) = make_ushort4(ov[4], ov[5], ov[6], ov[7]);
}

// ---------------- K4 fast: out = P @ xT^T, 2-phase dbuf, BK=64, batch->XCD ----------------
__global__ __launch_bounds__(512, 4) void k4_fast(const u16* __restrict__ P,
                                                  const u16* __restrict__ XT,
                                                  float* __restrict__ out)
{
    __shared__ u16 As[2][128 * 64];
    __shared__ u16 Bs[2][128 * 64];
    const int tid = threadIdx.x;
    const int lane = tid & 63, wid = tid >> 6;
    const int wr = (wid >> 1) * 32, wc = (wid & 1) * 64;
    const int l15 = lane & 15, q = lane >> 4;
    const int sw = l15 & 7;
    // batch->XCD swizzle: flat grid of 1024 = 8 d-blk x 16 it x 8 batches.
    // b = lin&7 pins batch b to XCD b; XT[b] = 4MiB = one XCD's L2.
    const int lin = blockIdx.x;
    const int b = lin & 7;
    const int r8 = lin >> 3;                     // 0..127
    const int d0 = (r8 & 7) * 128;
    const int it = (T_ / 128 - 1) - (r8 >> 3);   // heavy tiles first
    const int t0 = it * 128;
    const u16* Pb = P + (size_t)b * T_ * T_ + (size_t)t0 * T_;
    const u16* Xb = XT + (size_t)(b * D_ + d0) * T_;

    floatx4 acc[2][4];
#pragma unroll
    for (int i = 0; i < 2; i++)
#pragma unroll
        for (int j = 0; j < 4; j++) acc[i][j] = (floatx4){0.f, 0.f, 0.f, 0.f};

    const int nt = (it + 1) * 2;      // K-steps of 64 up to t0+128 (>= 2)
    stage8(Pb, T_, 0, As[0], wid, lane);
    stage8(Xb, T_, 0, Bs[0], wid, lane);
    __syncthreads();
    int cur = 0;
    for (int t = 0; t < nt; t++) {
        if (t + 1 < nt) {
            stage8(Pb, T_, (t + 1) * 64, As[cur ^ 1], wid, lane);
            stage8(Xb, T_, (t + 1) * 64, Bs[cur ^ 1], wid, lane);
        }
        gemm_step(As[cur], Bs[cur], wr, wc, l15, q, sw, acc);
        __syncthreads();
        cur ^= 1;
    }
#pragma unroll
    for (int i = 0; i < 2; i++)
#pragma unroll
        for (int j = 0; j < 4; j++)
#pragma unroll
            for (int r = 0; r < 4; r++) {
                const int gt = t0 + wr + i * 16 + q * 4 + r;
                const int gd = d0 + wc + j * 16 + l15;
                out[(size_t)(b * T_ + gt) * D_ + gd] = acc[i][j][r];
            }
}

// ---------------- K4 fallback (round-4): scalar-gather B-stage ----------------
__global__ __launch_bounds__(256) void k4_fb(const u16* __restrict__ P,
                                             const float* __restrict__ x,
                                             float* __restrict__ out)
{
    __shared__ u16 As[128 * PIT];
    __shared__ u16 Bs[128 * PIT];
    const int tid = threadIdx.x;
    const int lane = tid & 63, wid = tid >> 6;
    const int wr = (wid >> 1) * 64, wc = (wid & 1) * 64;
    const int l15 = lane & 15, q = lane >> 4;
    const int it = (T_ / 128 - 1) - blockIdx.y;
    const int t0 = it * 128;
    const int d0 = blockIdx.x * 128;
    const int b = blockIdx.z;
    const u16* Pb = P + (size_t)b * T_ * T_;
    const float* xb = x + (size_t)b * T_ * D_;
    const int gn = tid & 127;
    const int kh0 = (tid >> 7) * 2;

    floatx4 acc[4][4];
#pragma unroll
    for (int i = 0; i < 4; i++)
#pragma unroll
        for (int j = 0; j < 4; j++) acc[i][j] = (floatx4){0.f, 0.f, 0.f, 0.f};

    const int kend = t0 + 128;
    for (int k0 = 0; k0 < kend; k0 += 32) {
        __syncthreads();
#pragma unroll
        for (int u = 0; u < 2; u++) {
            const int c = tid * 2 + u;
            const int row = c >> 2, off = c & 3;
            *(uint4*)&As[row * PIT + off * 8] =
                *(const uint4*)(Pb + (size_t)(t0 + row) * T_ + k0 + off * 8);
        }
#pragma unroll
        for (int u = 0; u < 2; u++) {
            const int kh = kh0 + u;
            float f[8];
#pragma unroll
            for (int j = 0; j < 8; j++)
                f[j] = xb[(size_t)(k0 + kh * 8 + j) * D_ + d0 + gn];
            uint4 pk = make_uint4(pkbf(f[0], f[1]), pkbf(f[2], f[3]),
                                  pkbf(f[4], f[5]), pkbf(f[6], f[7]));
            *(uint4*)&Bs[gn * PIT + kh * 8] = pk;
        }
        __syncthreads();
        short8 a[4], b2[4];
#pragma unroll
        for (int i = 0; i < 4; i++) a[i] = *(const short8*)&As[(wr + i * 16 + l15) * PIT + q * 8];
#pragma unroll
        for (int j = 0; j < 4; j++) b2[j] = *(const short8*)&Bs[(wc + j * 16 + l15) * PIT + q * 8];
#pragma unroll
        for (int i = 0; i < 4; i++)
#pragma unroll
            for (int j = 0; j < 4; j++)
                acc[i][j] = __builtin_amdgcn_mfma_f32_16x16x32_bf16(a[i], b2[j], acc[i][j], 0, 0, 0);
    }
#pragma unroll
    for (int i = 0; i < 4; i++)
#pragma unroll
        for (int j = 0; j < 4; j++)
#pragma unroll
            for (int r = 0; r < 4; r++) {
                const int gt = t0 + wr + i * 16 + q * 4 + r;
                const int gd = d0 + wc + j * 16 + l15;
                out[(size_t)(b * T_ + gt) * D_ + gd] = acc[i][j][r];
            }
}

extern "C" void kernel_launch(void* const* d_in, const int* in_sizes, int n_in,
                              void* d_out, int out_size, void* d_ws, size_t ws_size,
                              hipStream_t stream)
{
    const float* x    = (const float*)d_in[0];
    const float* W    = (const float*)d_in[1];
    const float* bias = (const float*)d_in[2];
    float* outf = (float*)d_out;
    u16*   y    = (u16*)d_out;                  // bf16, first 32 MiB of d_out
    u16*   WT   = y + ((size_t)1 << 24);        // 32MiB..34MiB of d_out (dead before k4)
    u16*   S    = (u16*)d_ws;                   // 64 MiB (m/r + partials in dead zones)
    u16*   xbf  = S;                            // bf16 x, ws[0:32MiB] (dead before k2)
    u16*   XT   = S + ((size_t)1 << 25);        // ws+64MiB..+96MiB (fast path only)
    const bool fast = ws_size >= ((size_t)96 << 20);

    dim3 g0(D_ / 64, E_ / 64);            // (16,16)
    k0_wt<<<g0, 256, 0, stream>>>(W, WT);

    dim3 g00(T_ / 64, D_ / 64, B_);       // (32,16,8)
    k00_xt<<<g00, 256, 0, stream>>>(x, XT, xbf, fast ? 1 : 0);

    dim3 g1(E_ / 128, (B_ * T_) / 128);   // (8, 128)
    k1_proj<<<g1, 512, 0, stream>>>(xbf, WT, bias, y);

    dim3 g2(136 * B_);                    // flat, batch->XCD
    k2_score<<<g2, 512, 0, stream>>>(y, S);

    dim3 gc(T_ / 256, B_);                // (8, 8)
    k2c_comb<<<gc, 256, 0, stream>>>(S);

    dim3 g3(B_ * T_);
    k3_pnorm<<<g3, 256, 0, stream>>>(S);

    dim3 g4((D_ / 128) * (T_ / 128) * B_);   // flat 1024, batch->XCD
    if (fast) k4_fast<<<g4, 512, 0, stream>>>(S, XT, outf);
    else {
        dim3 g4b(D_ / 128, T_ / 128, B_);
        k4_fb<<<g4b, 256, 0, stream>>>(S, x, outf);
    }
}

// Round 9
// 277.785 us; speedup vs baseline: 1.2094x; 1.0496x over previous
//
#include <hip/hip_runtime.h>
#include <hip/hip_bf16.h>

// B=8, T=2048, D=1024, E=1024
//   k0 : WT = bf16(W^T)                 -> d_out[32MiB..34MiB] (dead before k4)
//   k00: xbf = bf16(x) [B][T][D]        -> d_ws[0:32MiB]   (dead before k2 writes S)
//        xT  = bf16(x^T) [B][D][T]      -> d_ws[64MiB..96MiB] (only if ws >= 96MiB)
//   k1 : y = bf16(xbf@WT^T + b)         -> d_out[0:32MiB]  (2-phase dbuf MFMA, BK=64)
//   k2 : S[b,t,s] = bf16(y_t.y_s/32)    -> d_ws, lower-triangle tiles (BK=64)
//        + fused per-(tile,column) softmax partials (m,z) -> batch dead zone
//   k3_tile (fast): fused {combine partials -> m,1/z in LDS} + {P=exp(S-m)*r}
//        per 128x128 triangular tile, full thread utilization
//   k2c+k3 (fallback): round-8 versions
//   k4 : out = P @ x  fp32  — fast path: 2-phase dbuf from P and xT.
//
// Round-9: (a) k2 epilogue staging u16 ov[32] -> float fv[32] (register-friendly,
//   no b2f recompute; suspected scratch was the +8us of round 8). (b) k3+k2c
//   replaced by k3_tile: triangular-tile grid (136x8, batch->XCD), per-block
//   fused column-combine (<=16 L2-hot float2 merges/col -> LDS) + tile
//   normalize with 16B ld/st, no idle threads, no causal predication off the
//   diagonal. Deletes one launch + the mr-stash round trip on the fast path.
//
// MFMA 16x16x32 bf16 frag layouts (HW-verified):
//   A: lane holds A[m=lane&15][k=q*8+j]; B: B[k=q*8+j][n=lane&15]
//   C/D: lane,reg r -> D[row=q*4+r][col=lane&15]
// Swizzled LDS tile (128 rows x 64 shorts, no pad): 16B chunk slot c of row r
// holds logical chunk c ^ (r&7) (pre-swizzled global source, linear LDS dest).

#define B_ 8
#define T_ 2048
#define D_ 1024
#define E_ 1024
#define PIT 56

typedef unsigned short u16;
typedef __attribute__((ext_vector_type(8))) short short8;
typedef __attribute__((ext_vector_type(4))) float floatx4;

__device__ __forceinline__ float b2f(u16 u) {
    unsigned v = ((unsigned)u) << 16;
    float f; __builtin_memcpy(&f, &v, 4); return f;
}
__device__ __forceinline__ u16 f2b(float f) {
    unsigned v; __builtin_memcpy(&v, &f, 4);
    v = (v + 0x7FFFu + ((v >> 16) & 1u)) >> 16;   // RNE
    return (u16)v;
}
__device__ __forceinline__ unsigned pkbf(float a, float b) {
    __hip_bfloat162 h = __float22bfloat162_rn(make_float2(a, b));
    unsigned u; __builtin_memcpy(&u, &h, 4); return u;
}

// async 16B global -> LDS (lds dest = wave-uniform base + lane*16)
__device__ __forceinline__ void gl2lds16(const u16* gp, u16* lp) {
    __builtin_amdgcn_global_load_lds(
        (const __attribute__((address_space(1))) void*)(gp),
        (__attribute__((address_space(3))) void*)(lp), 16, 0, 0);
}

// 8-wave (512-thread) stage of a 128-row x 64-short bf16 tile into swizzled LDS.
__device__ __forceinline__ void stage8(const u16* src, size_t srow, int kc,
                                       u16* lds, int wid, int lane)
{
    const int rl = lane >> 3, c = lane & 7;
    const int g = ((c ^ rl) << 3);
#pragma unroll
    for (int cc = 0; cc < 2; cc++) {
        const int r = cc * 64 + wid * 8;
        gl2lds16(src + (size_t)(r + rl) * srow + kc + g, &lds[r * 64]);
    }
}

// one BK=64 MFMA step on a staged slot pair (16 mfma)
__device__ __forceinline__ void gemm_step(const u16* As_, const u16* Bs_,
                                          int wr, int wc, int l15, int q, int sw,
                                          floatx4 (&acc)[2][4])
{
#pragma unroll
    for (int h = 0; h < 2; h++) {
        short8 a[2], b2[4];
#pragma unroll
        for (int i = 0; i < 2; i++)
            a[i] = *(const short8*)&As_[(wr + i * 16 + l15) * 64 + (((h * 4 + q) ^ sw) << 3)];
#pragma unroll
        for (int j = 0; j < 4; j++)
            b2[j] = *(const short8*)&Bs_[(wc + j * 16 + l15) * 64 + (((h * 4 + q) ^ sw) << 3)];
#pragma unroll
        for (int i = 0; i < 2; i++)
#pragma unroll
            for (int j = 0; j < 4; j++)
                acc[i][j] = __builtin_amdgcn_mfma_f32_16x16x32_bf16(a[i], b2[j], acc[i][j], 0, 0, 0);
    }
}

// m/r stash inside S's strictly-upper dead zone (batch 0, rows 0..63, cols 1024+).
__device__ __forceinline__ float* mr_ptr(u16* S, int which, int b, int s) {
    const int row = which * 32 + b * 4 + (s >> 9);
    return (float*)(S + (size_t)row * T_ + 1024 + (s & 511) * 2);
}
// per-(it-tile, column) partial (m,z) float2 in batch b's dead zone,
// rows 64..191, cols 1024+ (dead vs k2 writes / k3 / k4 reads for rows<192).
__device__ __forceinline__ float2* part2_ptr(u16* S, int it, int b, int s) {
    const int row = 64 + it * 8 + (s >> 8);
    return (float2*)(S + (size_t)b * T_ * T_ + (size_t)row * T_ + 1024 + (s & 255) * 4);
}

// ---------------- K0: WT[n][k] = bf16(W[k][n]) ----------------
__global__ __launch_bounds__(256) void k0_wt(const float* __restrict__ W,
                                             u16* __restrict__ WT)
{
    __shared__ float Ws[64 * 68];
    const int tid = threadIdx.x;
    const int k0 = blockIdx.x * 64, n0 = blockIdx.y * 64;
#pragma unroll
    for (int u = 0; u < 4; u++) {
        const int c = tid + 256 * u;
        const int row = c >> 4, c4 = c & 15;
        float4 v = *(const float4*)(W + (size_t)(k0 + row) * E_ + n0 + c4 * 4);
        *(float4*)&Ws[row * 68 + c4 * 4] = v;
    }
    __syncthreads();
#pragma unroll
    for (int u = 0; u < 2; u++) {
        const int c = tid + 256 * u;
        const int n = c >> 3, kc = c & 7;
        unsigned pk[4];
#pragma unroll
        for (int j = 0; j < 4; j++)
            pk[j] = pkbf(Ws[(kc * 8 + 2 * j) * 68 + n], Ws[(kc * 8 + 2 * j + 1) * 68 + n]);
        *(uint4*)(WT + (size_t)(n0 + n) * D_ + k0 + kc * 8) = make_uint4(pk[0], pk[1], pk[2], pk[3]);
    }
}

// ---------------- K00: xbf = bf16(x); optionally xT[b][d][t] = bf16(x[b][t][d]) ----------------
__global__ __launch_bounds__(256) void k00_xt(const float* __restrict__ x,
                                              u16* __restrict__ XT,
                                              u16* __restrict__ xbf,
                                              int do_xt)
{
    __shared__ float Xs[64 * 68];
    const int tid = threadIdx.x;
    const int s0 = blockIdx.x * 64, d0 = blockIdx.y * 64, b = blockIdx.z;
    const float* xb = x + (size_t)b * T_ * D_;
#pragma unroll
    for (int u = 0; u < 4; u++) {
        const int c = tid + 256 * u;
        const int row = c >> 4, c4 = c & 15;
        float4 v = *(const float4*)(xb + (size_t)(s0 + row) * D_ + d0 + c4 * 4);
        *(float4*)&Xs[row * 68 + c4 * 4] = v;
    }
    __syncthreads();
    // row-major bf16 copy (always)
#pragma unroll
    for (int u = 0; u < 2; u++) {
        const int c = tid + 256 * u;
        const int row = c >> 3, off = c & 7;
        unsigned pk[4];
#pragma unroll
        for (int j = 0; j < 4; j++)
            pk[j] = pkbf(Xs[row * 68 + off * 8 + 2 * j], Xs[row * 68 + off * 8 + 2 * j + 1]);
        *(uint4*)(xbf + ((size_t)(b * T_ + s0 + row)) * D_ + d0 + off * 8) =
            make_uint4(pk[0], pk[1], pk[2], pk[3]);
    }
    if (!do_xt) return;
    // transposed bf16 copy (fast path only)
#pragma unroll
    for (int u = 0; u < 2; u++) {
        const int c = tid + 256 * u;
        const int d = c >> 3, sc = c & 7;
        unsigned pk[4];
#pragma unroll
        for (int j = 0; j < 4; j++)
            pk[j] = pkbf(Xs[(sc * 8 + 2 * j) * 68 + d], Xs[(sc * 8 + 2 * j + 1) * 68 + d]);
        *(uint4*)(XT + ((size_t)(b * D_ + d0 + d)) * T_ + s0 + sc * 8) =
            make_uint4(pk[0], pk[1], pk[2], pk[3]);
    }
}

// ---------------- K1: y = bf16(xbf @ WT^T + b), 2-phase dbuf, BK=64 ----------------
__global__ __launch_bounds__(512, 4) void k1_proj(const u16* __restrict__ xbf,
                                                  const u16* __restrict__ WT,
                                                  const float* __restrict__ bias,
                                                  u16* __restrict__ y)
{
    __shared__ u16 As[2][128 * 64];
    __shared__ u16 Bs[2][128 * 64];
    const int tid = threadIdx.x;
    const int lane = tid & 63, wid = tid >> 6;
    const int wr = (wid >> 1) * 32, wc = (wid & 1) * 64;
    const int l15 = lane & 15, q = lane >> 4;
    const int sw = l15 & 7;
    // XCD-chunked swizzle: XCD c owns m-tiles [16c,16c+16) (A panel ~4MB -> L2-hot)
    const int lin = blockIdx.y * 8 + blockIdx.x;      // 1024 blocks, %8==0
    const int v = (lin & 7) * 128 + (lin >> 3);
    const int n0 = (v & 7) * 128, m0 = (v >> 3) * 128;
    const u16* Ab = xbf + (size_t)m0 * D_;
    const u16* Bb = WT + (size_t)n0 * D_;

    floatx4 acc[2][4];
#pragma unroll
    for (int i = 0; i < 2; i++)
#pragma unroll
        for (int j = 0; j < 4; j++) acc[i][j] = (floatx4){0.f, 0.f, 0.f, 0.f};

    stage8(Ab, D_, 0, As[0], wid, lane);
    stage8(Bb, D_, 0, Bs[0], wid, lane);
    __syncthreads();
    int cur = 0;
    for (int t = 0; t < 16; t++) {
        if (t + 1 < 16) {
            stage8(Ab, D_, (t + 1) * 64, As[cur ^ 1], wid, lane);
            stage8(Bb, D_, (t + 1) * 64, Bs[cur ^ 1], wid, lane);
        }
        gemm_step(As[cur], Bs[cur], wr, wc, l15, q, sw, acc);
        __syncthreads();
        cur ^= 1;
    }
    float bv[4];
#pragma unroll
    for (int j = 0; j < 4; j++) bv[j] = bias[n0 + wc + j * 16 + l15];
#pragma unroll
    for (int i = 0; i < 2; i++)
#pragma unroll
        for (int j = 0; j < 4; j++)
#pragma unroll
            for (int r = 0; r < 4; r++) {
                const int gm = m0 + wr + i * 16 + q * 4 + r;
                const int gn = n0 + wc + j * 16 + l15;
                y[(size_t)gm * E_ + gn] = f2b(acc[i][j][r] + bv[j]);
            }
}

// ---------------- K2: S tiles + fused column-stat partials, BK=64, batch->XCD ----------------
__global__ __launch_bounds__(512, 4) void k2_score(const u16* __restrict__ y,
                                                   u16* __restrict__ S)
{
    __shared__ u16 As[2][128 * 64];
    __shared__ u16 Bs[2][128 * 64];
    __shared__ float smf[8][64], smz[8][64];
    const int tid = threadIdx.x;
    const int lane = tid & 63, wid = tid >> 6;
    const int wr = (wid >> 1) * 32, wc = (wid & 1) * 64;
    const int l15 = lane & 15, q = lane >> 4;
    const int sw = l15 & 7;
    // batch->XCD swizzle: flat grid of 1088 = 136 tiles x 8 batches.
    const int lin = blockIdx.x;
    const int b = lin & 7;
    int idx = lin >> 3;                  // 0..135 triangular tile id
    int it = 0, base = 0;
    while (base + it + 1 <= idx) { base += it + 1; it++; }
    const int js = idx - base;
    const int t0 = it * 128, s0 = js * 128;
    const u16* yb = y + (size_t)b * T_ * E_;
    const u16* Ab = yb + (size_t)t0 * E_;
    const u16* Bb = yb + (size_t)s0 * E_;

    floatx4 acc[2][4];
#pragma unroll
    for (int i = 0; i < 2; i++)
#pragma unroll
        for (int j = 0; j < 4; j++) acc[i][j] = (floatx4){0.f, 0.f, 0.f, 0.f};

    stage8(Ab, E_, 0, As[0], wid, lane);
    stage8(Bb, E_, 0, Bs[0], wid, lane);
    __syncthreads();
    int cur = 0;
    for (int t = 0; t < 16; t++) {
        if (t + 1 < 16) {
            stage8(Ab, E_, (t + 1) * 64, As[cur ^ 1], wid, lane);
            stage8(Bb, E_, (t + 1) * 64, Bs[cur ^ 1], wid, lane);
        }
        gemm_step(As[cur], Bs[cur], wr, wc, l15, q, sw, acc);
        __syncthreads();
        cur ^= 1;
    }
    // ---- epilogue: write tile + per-thread (m,z) on bf16-rounded values ----
    // float staging (register-friendly; round-8's u16 array risked scratch)
    float fv[2][4][4];
    float pm[4] = {-1e38f, -1e38f, -1e38f, -1e38f};
    float pz[4] = {0.f, 0.f, 0.f, 0.f};
#pragma unroll
    for (int i = 0; i < 2; i++)
#pragma unroll
        for (int j = 0; j < 4; j++)
#pragma unroll
            for (int r = 0; r < 4; r++) {
                const int t = t0 + wr + i * 16 + q * 4 + r;
                const int s = s0 + wc + j * 16 + l15;
                u16 o = (t < s) ? (u16)0xFF7F : f2b(acc[i][j][r] * 0.03125f);
                S[((size_t)(b * T_ + t)) * T_ + s] = o;
                const float fo = b2f(o);
                fv[i][j][r] = fo;
                if (t >= s) pm[j] = fmaxf(pm[j], fo);
            }
#pragma unroll
    for (int i = 0; i < 2; i++)
#pragma unroll
        for (int j = 0; j < 4; j++)
#pragma unroll
            for (int r = 0; r < 4; r++) {
                const int t = t0 + wr + i * 16 + q * 4 + r;
                const int s = s0 + wc + j * 16 + l15;
                const float ez = __expf(fv[i][j][r] - pm[j]);
                pz[j] += (t >= s) ? ez : 0.f;
            }
    // merge across the 4 q-lanes sharing each column (lane ^16, ^32)
#pragma unroll
    for (int j = 0; j < 4; j++) {
#pragma unroll
        for (int d = 16; d < 64; d <<= 1) {
            const float om = __shfl_xor(pm[j], d);
            const float oz = __shfl_xor(pz[j], d);
            const float nm = fmaxf(pm[j], om);
            pz[j] = pz[j] * __expf(pm[j] - nm) + oz * __expf(om - nm);
            pm[j] = nm;
        }
    }
    if (q == 0)
#pragma unroll
        for (int j = 0; j < 4; j++) {
            smf[wid][j * 16 + l15] = pm[j];
            smz[wid][j * 16 + l15] = pz[j];
        }
    __syncthreads();
    if (tid < 128) {   // one thread per tile column: merge the 4 row-wave groups
        const int half = tid >> 6, cidx = tid & 63;
        float M = -1e38f, Z = 0.f;
#pragma unroll
        for (int g = 0; g < 4; g++) {
            const float m2 = smf[g * 2 + half][cidx];
            const float z2 = smz[g * 2 + half][cidx];
            const float nm = fmaxf(M, m2);
            Z = Z * __expf(M - nm) + z2 * __expf(m2 - nm);
            M = nm;
        }
        *part2_ptr(S, it, b, s0 + half * 64 + cidx) = make_float2(M, Z);
    }
}

// ---------------- K3_tile (fast): fused combine + normalize per 128x128 tile ----------------
__global__ __launch_bounds__(256) void k3_tile(u16* __restrict__ S)
{
    __shared__ float lm[128], lr[128];
    const int tid = threadIdx.x;
    const int lin = blockIdx.x;            // 1088 = 136 tiles x 8 batches
    const int b = lin & 7;                 // batch->XCD
    int idx = lin >> 3, it = 0, base = 0;
    while (base + it + 1 <= idx) { base += it + 1; it++; }
    const int js = idx - base;
    const int t0 = it * 128, s0 = js * 128;
    // phase 1: combine this column strip's partials (L2-hot, redundant per it)
    if (tid < 128) {
        const int s = s0 + tid;
        float M = -1e38f, Z = 0.f;
        for (int i2 = js; i2 < 16; i2++) {
            const float2 p = *part2_ptr(S, i2, b, s);
            const float nm = fmaxf(M, p.x);
            Z = Z * __expf(M - nm) + p.y * __expf(p.x - nm);
            M = nm;
        }
        lm[tid] = M;
        lr[tid] = 1.0f / Z;
    }
    __syncthreads();
    // phase 2: normalize the tile. thread -> col chunk (tid&15)*8, rows tid>>4 + 16*rr
    u16* Sb = S + (size_t)b * T_ * T_;
    const int c8 = (tid & 15) * 8;
    const int r0 = tid >> 4;
    float mv[8], rv[8];
    *(float4*)&mv[0] = *(const float4*)&lm[c8];
    *(float4*)&mv[4] = *(const float4*)&lm[c8 + 4];
    *(float4*)&rv[0] = *(const float4*)&lr[c8];
    *(float4*)&rv[4] = *(const float4*)&lr[c8 + 4];
    const bool diag = (it == js);
#pragma unroll
    for (int rr = 0; rr < 8; rr++) {
        const int t = t0 + r0 + rr * 16;
        u16* Sp = Sb + (size_t)t * T_ + s0 + c8;
        ushort4 v0 = *(ushort4*)Sp;
        ushort4 v1 = *(ushort4*)(Sp + 4);
        u16 vv[8] = { v0.x, v0.y, v0.z, v0.w, v1.x, v1.y, v1.z, v1.w };
        u16 ov[8];
#pragma unroll
        for (int i = 0; i < 8; i++) {
            float p = __expf(b2f(vv[i]) - mv[i]) * rv[i];
            if (diag && (s0 + c8 + i > t)) p = 0.f;
            ov[i] = f2b(p);
        }
        *(ushort4*)Sp       = make_ushort4(ov[0], ov[1], ov[2], ov[3]);
        *(ushort4*)(Sp + 4) = make_ushort4(ov[4], ov[5], ov[6], ov[7]);
    }
}

// ---------------- K2c_comb (fallback): combine <=16 it-partials -> (m, 1/z) stash ----------------
__global__ __launch_bounds__(256) void k2c_comb(u16* __restrict__ S)
{
    const int s = blockIdx.x * 256 + threadIdx.x;
    const int b = blockIdx.y;
    float M = -1e38f, Z = 0.f;
    for (int it = s >> 7; it < 16; it++) {   // tiles above the diagonal never wrote
        const float2 p = *part2_ptr(S, it, b, s);
        const float nm = fmaxf(M, p.x);
        Z = Z * __expf(M - nm) + p.y * __expf(p.x - nm);
        M = nm;
    }
    *mr_ptr(S, 0, b, s) = M;
    *mr_ptr(S, 1, b, s) = 1.0f / Z;
}

// ---------------- K3 (fallback): P = exp(S - m_s) * r_s ----------------
__global__ __launch_bounds__(256) void k3_pnorm(u16* __restrict__ S)
{
    const int row = blockIdx.x;          // b*T + t
    const int b = row >> 11;
    const int t = row & (T_ - 1);
    const int sEnd = ((t >> 7) + 1) << 7;
    const int s0 = threadIdx.x * 8;
    if (s0 >= sEnd) return;
    u16* Sp = S + (size_t)row * T_ + s0;
    const float* mp = mr_ptr(S, 0, b, s0);
    const float* rp = mr_ptr(S, 1, b, s0);
    float mv[8], rv[8];
    *(float4*)&mv[0] = *(const float4*)mp;
    *(float4*)&mv[4] = *((const float4*)mp + 1);
    *(float4*)&rv[0] = *(const float4*)rp;
    *(float4*)&rv[4] = *((const float4*)rp + 1);
    ushort4 v0 = *(ushort4*)Sp;
    ushort4 v1 = *(ushort4*)(Sp + 4);
    u16 vv[8] = { v0.x, v0.y, v0.z, v0.w, v1.x, v1.y, v1.z, v1.w };
    u16 ov[8];
#pragma unroll
    for (int i = 0; i < 8; i++) {
        const int s = s0 + i;
        float p = 0.f;
        if (s <= t) p = __expf(b2f(vv[i]) - mv[i]) * rv[i];
        ov[i] = f2b(p);
    }
    *(ushort4*)Sp       = make_ushort4(ov[0], ov[1], ov[2], ov[3]);
    *(ushort4*)(Sp + 4) = make_ushort4(ov[4], ov[5], ov[6], ov[7]);
}

// ---------------- K4 fast: out = P @ xT^T, 2-phase dbuf, BK=64, batch->XCD ----------------
__global__ __launch_bounds__(512, 4) void k4_fast(const u16* __restrict__ P,
                                                  const u16* __restrict__ XT,
                                                  float* __restrict__ out)
{
    __shared__ u16 As[2][128 * 64];
    __shared__ u16 Bs[2][128 * 64];
    const int tid = threadIdx.x;
    const int lane = tid & 63, wid = tid >> 6;
    const int wr = (wid >> 1) * 32, wc = (wid & 1) * 64;
    const int l15 = lane & 15, q = lane >> 4;
    const int sw = l15 & 7;
    // batch->XCD swizzle: flat grid of 1024 = 8 d-blk x 16 it x 8 batches.
    const int lin = blockIdx.x;
    const int b = lin & 7;
    const int r8 = lin >> 3;                     // 0..127
    const int d0 = (r8 & 7) * 128;
    const int it = (T_ / 128 - 1) - (r8 >> 3);   // heavy tiles first
    const int t0 = it * 128;
    const u16* Pb = P + (size_t)b * T_ * T_ + (size_t)t0 * T_;
    const u16* Xb = XT + (size_t)(b * D_ + d0) * T_;

    floatx4 acc[2][4];
#pragma unroll
    for (int i = 0; i < 2; i++)
#pragma unroll
        for (int j = 0; j < 4; j++) acc[i][j] = (floatx4){0.f, 0.f, 0.f, 0.f};

    const int nt = (it + 1) * 2;      // K-steps of 64 up to t0+128 (>= 2)
    stage8(Pb, T_, 0, As[0], wid, lane);
    stage8(Xb, T_, 0, Bs[0], wid, lane);
    __syncthreads();
    int cur = 0;
    for (int t = 0; t < nt; t++) {
        if (t + 1 < nt) {
            stage8(Pb, T_, (t + 1) * 64, As[cur ^ 1], wid, lane);
            stage8(Xb, T_, (t + 1) * 64, Bs[cur ^ 1], wid, lane);
        }
        gemm_step(As[cur], Bs[cur], wr, wc, l15, q, sw, acc);
        __syncthreads();
        cur ^= 1;
    }
#pragma unroll
    for (int i = 0; i < 2; i++)
#pragma unroll
        for (int j = 0; j < 4; j++)
#pragma unroll
            for (int r = 0; r < 4; r++) {
                const int gt = t0 + wr + i * 16 + q * 4 + r;
                const int gd = d0 + wc + j * 16 + l15;
                out[(size_t)(b * T_ + gt) * D_ + gd] = acc[i][j][r];
            }
}

// ---------------- K4 fallback (round-4): scalar-gather B-stage ----------------
__global__ __launch_bounds__(256) void k4_fb(const u16* __restrict__ P,
                                             const float* __restrict__ x,
                                             float* __restrict__ out)
{
    __shared__ u16 As[128 * PIT];
    __shared__ u16 Bs[128 * PIT];
    const int tid = threadIdx.x;
    const int lane = tid & 63, wid = tid >> 6;
    const int wr = (wid >> 1) * 64, wc = (wid & 1) * 64;
    const int l15 = lane & 15, q = lane >> 4;
    const int it = (T_ / 128 - 1) - blockIdx.y;
    const int t0 = it * 128;
    const int d0 = blockIdx.x * 128;
    const int b = blockIdx.z;
    const u16* Pb = P + (size_t)b * T_ * T_;
    const float* xb = x + (size_t)b * T_ * D_;
    const int gn = tid & 127;
    const int kh0 = (tid >> 7) * 2;

    floatx4 acc[4][4];
#pragma unroll
    for (int i = 0; i < 4; i++)
#pragma unroll
        for (int j = 0; j < 4; j++) acc[i][j] = (floatx4){0.f, 0.f, 0.f, 0.f};

    const int kend = t0 + 128;
    for (int k0 = 0; k0 < kend; k0 += 32) {
        __syncthreads();
#pragma unroll
        for (int u = 0; u < 2; u++) {
            const int c = tid * 2 + u;
            const int row = c >> 2, off = c & 3;
            *(uint4*)&As[row * PIT + off * 8] =
                *(const uint4*)(Pb + (size_t)(t0 + row) * T_ + k0 + off * 8);
        }
#pragma unroll
        for (int u = 0; u < 2; u++) {
            const int kh = kh0 + u;
            float f[8];
#pragma unroll
            for (int j = 0; j < 8; j++)
                f[j] = xb[(size_t)(k0 + kh * 8 + j) * D_ + d0 + gn];
            uint4 pk = make_uint4(pkbf(f[0], f[1]), pkbf(f[2], f[3]),
                                  pkbf(f[4], f[5]), pkbf(f[6], f[7]));
            *(uint4*)&Bs[gn * PIT + kh * 8] = pk;
        }
        __syncthreads();
        short8 a[4], b2[4];
#pragma unroll
        for (int i = 0; i < 4; i++) a[i] = *(const short8*)&As[(wr + i * 16 + l15) * PIT + q * 8];
#pragma unroll
        for (int j = 0; j < 4; j++) b2[j] = *(const short8*)&Bs[(wc + j * 16 + l15) * PIT + q * 8];
#pragma unroll
        for (int i = 0; i < 4; i++)
#pragma unroll
            for (int j = 0; j < 4; j++)
                acc[i][j] = __builtin_amdgcn_mfma_f32_16x16x32_bf16(a[i], b2[j], acc[i][j], 0, 0, 0);
    }
#pragma unroll
    for (int i = 0; i < 4; i++)
#pragma unroll
        for (int j = 0; j < 4; j++)
#pragma unroll
            for (int r = 0; r < 4; r++) {
                const int gt = t0 + wr + i * 16 + q * 4 + r;
                const int gd = d0 + wc + j * 16 + l15;
                out[(size_t)(b * T_ + gt) * D_ + gd] = acc[i][j][r];
            }
}

extern "C" void kernel_launch(void* const* d_in, const int* in_sizes, int n_in,
                              void* d_out, int out_size, void* d_ws, size_t ws_size,
                              hipStream_t stream)
{
    const float* x    = (const float*)d_in[0];
    const float* W    = (const float*)d_in[1];
    const float* bias = (const float*)d_in[2];
    float* outf = (float*)d_out;
    u16*   y    = (u16*)d_out;                  // bf16, first 32 MiB of d_out
    u16*   WT   = y + ((size_t)1 << 24);        // 32MiB..34MiB of d_out (dead before k4)
    u16*   S    = (u16*)d_ws;                   // 64 MiB (m/r + partials in dead zones)
    u16*   xbf  = S;                            // bf16 x, ws[0:32MiB] (dead before k2)
    u16*   XT   = S + ((size_t)1 << 25);        // ws+64MiB..+96MiB (fast path only)
    const bool fast = ws_size >= ((size_t)96 << 20);

    dim3 g0(D_ / 64, E_ / 64);            // (16,16)
    k0_wt<<<g0, 256, 0, stream>>>(W, WT);

    dim3 g00(T_ / 64, D_ / 64, B_);       // (32,16,8)
    k00_xt<<<g00, 256, 0, stream>>>(x, XT, xbf, fast ? 1 : 0);

    dim3 g1(E_ / 128, (B_ * T_) / 128);   // (8, 128)
    k1_proj<<<g1, 512, 0, stream>>>(xbf, WT, bias, y);

    dim3 g2(136 * B_);                    // flat, batch->XCD
    k2_score<<<g2, 512, 0, stream>>>(y, S);

    dim3 g4((D_ / 128) * (T_ / 128) * B_);   // flat 1024, batch->XCD
    if (fast) {
        dim3 g3t(136 * B_);               // flat, batch->XCD
        k3_tile<<<g3t, 256, 0, stream>>>(S);
        k4_fast<<<g4, 512, 0, stream>>>(S, XT, outf);
    } else {
        dim3 gc(T_ / 256, B_);            // (8, 8)
        k2c_comb<<<gc, 256, 0, stream>>>(S);
        dim3 g3(B_ * T_);
        k3_pnorm<<<g3, 256, 0, stream>>>(S);
        dim3 g4b(D_ / 128, T_ / 128, B_);
        k4_fb<<<g4b, 256, 0, stream>>>(S, x, outf);
    }
}